// Round 1
// baseline (1024.002 us; speedup 1.0000x reference)
//
#include <hip/hip_runtime.h>

#define AANG 180
#define NN 256
#define BCH 12

#ifndef M_PI
#define M_PI 3.14159265358979323846
#endif

__device__ __forceinline__ int iclamp(int v, int lo, int hi) {
    return v < lo ? lo : (v > hi ? hi : v);
}

// ---------------- Radon: one block per (image, angle); thread = output column x,
// loop over rows y, bilinear sample of rotated coords, accumulate. ----------------
__global__ void radon_kernel(const float* __restrict__ x, float* __restrict__ sino) {
    int blk = blockIdx.x;
    int n = blk / AANG;
    int a = blk - n * AANG;
    const float* img = x + (size_t)n * NN * NN;
    int tx = threadIdx.x;  // output column
    float th = (float)((double)a * (M_PI / 180.0));
    float c = cosf(th), s = sinf(th);
    float fx = (float)tx;
    float kx = -128.0f * (c + s - 1.0f);
    float ky = -128.0f * (c - s - 1.0f);
    float acc = 0.0f;
    for (int y = 0; y < NN; ++y) {
        float fy = (float)y;
        float sx = c * fx + s * fy + kx;   // source col
        float sy = -s * fx + c * fy + ky;  // source row
        float ixf = floorf(sx), iyf = floorf(sy);
        int ix = (int)ixf, iy = (int)iyf;
        float wx = sx - ixf, wy = sy - iyf;
        bool x0 = (ix >= 0) && (ix < NN);
        bool x1 = (ix + 1 >= 0) && (ix + 1 < NN);
        bool y0 = (iy >= 0) && (iy < NN);
        bool y1 = (iy + 1 >= 0) && (iy + 1 < NN);
        float v00 = (x0 && y0) ? img[iy * NN + ix] : 0.0f;
        float v01 = (x1 && y0) ? img[iy * NN + ix + 1] : 0.0f;
        float v10 = (x0 && y1) ? img[(iy + 1) * NN + ix] : 0.0f;
        float v11 = (x1 && y1) ? img[(iy + 1) * NN + ix + 1] : 0.0f;
        float val = (1.0f - wy) * ((1.0f - wx) * v00 + wx * v01) +
                    wy * ((1.0f - wx) * v10 + wx * v11);
        acc += val;
    }
    sino[((size_t)n * NN + tx) * AANG + a] = acc;  // sino[n][x][a]
}

// ---------------- QKV: one block per (n, i); thread j computes Q/K/V[n,i,j]. ----
__global__ void qkv_kernel(const float* __restrict__ sino,
                           const float* __restrict__ Wq, const float* __restrict__ bq,
                           const float* __restrict__ Wk, const float* __restrict__ bk,
                           const float* __restrict__ Wv, const float* __restrict__ bv,
                           float* __restrict__ Q, float* __restrict__ K,
                           float* __restrict__ V) {
    __shared__ float srow[AANG];
    int blk = blockIdx.x;  // n*NN + i
    int tid = threadIdx.x;
    if (tid < AANG) srow[tid] = sino[(size_t)blk * AANG + tid];
    __syncthreads();
    if (tid < AANG) {
        const float* wq = Wq + (size_t)tid * AANG;
        const float* wk = Wk + (size_t)tid * AANG;
        const float* wv = Wv + (size_t)tid * AANG;
        float aq = bq[tid], ak = bk[tid], av = bv[tid];
        for (int p = 0; p < AANG; ++p) {
            float sv = srow[p];
            aq += sv * wq[p];
            ak += sv * wk[p];
            av += sv * wv[p];
        }
        size_t o = (size_t)blk * AANG + tid;
        Q[o] = aq; K[o] = ak; V[o] = av;
    }
}

// ---------------- Attention: one block per (n, i). 256 threads: thread k computes
// logit_k = Q_i . K_k / sqrt(180); block softmax; then thread j<180 does PV. ----
__global__ void attn_kernel(const float* __restrict__ Q, const float* __restrict__ K,
                            const float* __restrict__ V, float* __restrict__ att) {
    __shared__ float qrow[AANG];
    __shared__ float prob[NN];
    __shared__ float red[NN];
    int blk = blockIdx.x;  // n*NN + i
    int n = blk >> 8;
    int tid = threadIdx.x;
    if (tid < AANG) qrow[tid] = Q[(size_t)blk * AANG + tid];
    __syncthreads();
    const float* krow = K + ((size_t)n * NN + tid) * AANG;
    float dot = 0.0f;
    for (int j = 0; j < AANG; ++j) dot += qrow[j] * krow[j];
    float logit = dot / sqrtf((float)AANG);
    // max reduction
    red[tid] = logit;
    __syncthreads();
    for (int s = NN / 2; s > 0; s >>= 1) {
        if (tid < s) red[tid] = fmaxf(red[tid], red[tid + s]);
        __syncthreads();
    }
    float mx = red[0];
    __syncthreads();
    float e = expf(logit - mx);
    red[tid] = e;
    __syncthreads();
    for (int s = NN / 2; s > 0; s >>= 1) {
        if (tid < s) red[tid] += red[tid + s];
        __syncthreads();
    }
    float denom = red[0];
    prob[tid] = e / denom;
    __syncthreads();
    if (tid < AANG) {
        float acc = 0.0f;
        const float* vb = V + (size_t)n * NN * AANG + tid;
        for (int k = 0; k < NN; ++k) acc += prob[k] * vb[(size_t)k * AANG];
        att[(size_t)blk * AANG + tid] = acc;
    }
}

// ---------------- Ramp filter as direct 128-tap symmetric convolution.
// filtered[i] = 0.5*s[i] - (2/pi^2) * sum_{odd d} (s[i-d]+s[i+d])/d^2
// Output transposed: filt[n][a][i] so backproj reads contiguous columns. ----
__global__ void filter_kernel(const float* __restrict__ att, float* __restrict__ filt) {
    __shared__ float col[NN];
    __shared__ float coef[128];
    int blk = blockIdx.x;  // n*AANG + a
    int n = blk / AANG;
    int a = blk - n * AANG;
    int tid = threadIdx.x;
    col[tid] = att[((size_t)n * NN + tid) * AANG + a];
    if (tid < 128) {
        double d = (double)(2 * tid + 1);
        coef[tid] = (float)(-2.0 / (M_PI * M_PI * d * d));
    }
    __syncthreads();
    float acc = 0.5f * col[tid];
    for (int m = 0; m < 128; ++m) {
        int d = 2 * m + 1;
        float lo = (tid - d >= 0) ? col[tid - d] : 0.0f;
        float hi = (tid + d < NN) ? col[tid + d] : 0.0f;
        acc += coef[m] * (lo + hi);
    }
    filt[((size_t)n * AANG + a) * NN + tid] = acc;
}

// ---------------- Backprojection: one block per (n, output row r); thread = col c.
// Stage each angle's filtered column (256 floats) in LDS, lerp, accumulate. ----
__global__ void backproj_kernel(const float* __restrict__ filt, float* __restrict__ out) {
    __shared__ float col[NN];
    __shared__ float cs[AANG], sn[AANG];
    int blk = blockIdx.x;  // n*NN + r
    int n = blk >> 8;
    int r = blk & 255;
    int tid = threadIdx.x;  // column c
    if (tid < AANG) {
        float th = (float)((double)tid * (M_PI / 180.0));
        cs[tid] = cosf(th);
        sn[tid] = sinf(th);
    }
    float xr = (float)(r - 128);   // xpr (row - radius)
    float yr = (float)(tid - 128); // ypr (col - radius)
    float acc = 0.0f;
    const float* fb = filt + (size_t)n * AANG * NN;
    for (int a = 0; a < AANG; ++a) {
        __syncthreads();
        col[tid] = fb[(size_t)a * NN + tid];
        __syncthreads();
        float t = yr * cs[a] - xr * sn[a] + 128.0f;
        float i0f = floorf(t);
        int i0 = (int)i0f;
        float frac = t - i0f;
        int c0 = iclamp(i0, 0, NN - 1);
        int c1 = iclamp(i0 + 1, 0, NN - 1);
        float val = (1.0f - frac) * col[c0] + frac * col[c1];
        if (t >= 0.0f && t <= 255.0f) acc += val;
    }
    bool inside = (xr * xr + yr * yr) <= 16384.0f;
    out[(size_t)blk * NN + tid] = inside ? acc * (float)(M_PI / 360.0) : 0.0f;
}

extern "C" void kernel_launch(void* const* d_in, const int* in_sizes, int n_in,
                              void* d_out, int out_size, void* d_ws, size_t ws_size,
                              hipStream_t stream) {
    const float* x  = (const float*)d_in[0];
    const float* Wq = (const float*)d_in[1];
    const float* bq = (const float*)d_in[2];
    const float* Wk = (const float*)d_in[3];
    const float* bk = (const float*)d_in[4];
    const float* Wv = (const float*)d_in[5];
    const float* bv = (const float*)d_in[6];
    float* out = (float*)d_out;
    float* ws = (float*)d_ws;

    const size_t SZ = (size_t)BCH * NN * AANG;  // 552960 floats per buffer
    float* sino = ws;
    float* Q    = sino + SZ;
    float* K    = Q + SZ;
    float* V    = K + SZ;
    float* att  = V + SZ;
    float* filt = att + SZ;  // total 6*SZ*4 = 13.3 MB of ws

    radon_kernel<<<BCH * AANG, NN, 0, stream>>>(x, sino);
    qkv_kernel<<<BCH * NN, 192, 0, stream>>>(sino, Wq, bq, Wk, bk, Wv, bv, Q, K, V);
    attn_kernel<<<BCH * NN, NN, 0, stream>>>(Q, K, V, att);
    filter_kernel<<<BCH * AANG, NN, 0, stream>>>(att, filt);
    backproj_kernel<<<BCH * NN, NN, 0, stream>>>(filt, out);
}

// Round 2
// 860.373 us; speedup vs baseline: 1.1902x; 1.1902x over previous
//
#include <hip/hip_runtime.h>

#define AANG 180
#define NN 256
#define BCH 12

#ifndef M_PI
#define M_PI 3.14159265358979323846
#endif

__device__ __forceinline__ int iclamp(int v, int lo, int hi) {
    return v < lo ? lo : (v > hi ? hi : v);
}

// ---------------- Radon v3: LDS row-band staging.
// Bands over iy: [-1,51],[52,103],[104,155],[156,207],[208,259].
// Stage rows [lo, lo+53], padded cols (-1..257) into LDS; each thread binary-
// searches its y-interval per band (sy monotone in y), samples bilinear from LDS.
#define BAND 52
#define LROWS 54
#define LSTR 259

__global__ void radon_kernel(const float* __restrict__ x, float* __restrict__ sino) {
    __shared__ float tile[LROWS * LSTR];  // 55.9 KB
    int blk = blockIdx.x;
    int n = blk / AANG;
    int a = blk - n * AANG;
    const float* img = x + (size_t)n * NN * NN;
    int tid = threadIdx.x;  // output column fx
    float th = (float)((double)a * (M_PI / 180.0));
    float c = cosf(th), s = sinf(th);
    float fx = (float)tid;
    float kx = -128.0f * (c + s - 1.0f);
    float ky = -128.0f * (c - s - 1.0f);
    float dcon = -s * fx + ky;  // sy = fma(c, fy, dcon)
    float xcon = c * fx + kx;   // sx = fma(s, fy, xcon)
    bool rev = (c < 0.0f);      // make iy(u) non-decreasing in u
    float acc = 0.0f;
    for (int b = 0; b < 5; ++b) {
        int lo = (b == 0) ? -1 : b * BAND;
        int hi = (b + 1) * BAND - 1;
        if (b) __syncthreads();
        // stage rows [lo, lo+LROWS-1], LDS col lc = global col + 1
        for (int idx = tid; idx < LROWS * LSTR; idx += NN) {
            int lr = idx / LSTR;
            int lc = idx - lr * LSTR;
            int gr = lo + lr;
            int gc = lc - 1;
            float v = 0.0f;
            if (gr >= 0 && gr < NN && gc >= 0 && gc < NN) v = img[gr * NN + gc];
            tile[idx] = v;
        }
        __syncthreads();
        // lower bound: first u with iy(u) >= lo
        int u0;
        {
            int l = 0, h = 256;
            while (l < h) {
                int m = (l + h) >> 1;
                float fy = rev ? (float)(255 - m) : (float)m;
                int iy = (int)floorf(__builtin_fmaf(c, fy, dcon));
                if (iy >= lo) h = m; else l = m + 1;
            }
            u0 = l;
        }
        // upper bound: first u with iy(u) > hi
        int u1;
        {
            int l = u0, h = 256;
            while (l < h) {
                int m = (l + h) >> 1;
                float fy = rev ? (float)(255 - m) : (float)m;
                int iy = (int)floorf(__builtin_fmaf(c, fy, dcon));
                if (iy > hi) h = m; else l = m + 1;
            }
            u1 = l;
        }
        for (int u = u0; u < u1; ++u) {
            float fy = rev ? (float)(255 - u) : (float)u;
            float sy = __builtin_fmaf(c, fy, dcon);
            float sx = __builtin_fmaf(s, fy, xcon);
            float iyf = floorf(sy), ixf = floorf(sx);
            int iy = (int)iyf, ix = (int)ixf;
            float wy = sy - iyf, wx = sx - ixf;
            int lr = iclamp(iy - lo, 0, LROWS - 2);  // in-band by construction; clamp = safety
            bool okx = (ix >= -1) && (ix <= NN);
            int lc = okx ? (ix + 1) : 0;
            const float* t0 = &tile[lr * LSTR + lc];
            float v00 = t0[0], v01 = t0[1];
            float v10 = t0[LSTR], v11 = t0[LSTR + 1];
            float wx1 = 1.0f - wx, wy1 = 1.0f - wy;
            float val = wy1 * (wx1 * v00 + wx * v01) + wy * (wx1 * v10 + wx * v11);
            acc += okx ? val : 0.0f;
        }
    }
    sino[((size_t)(n * NN) + tid) * AANG + a] = acc;  // sino[n][x][a]
}

// ---------------- W transpose: WT[p][j] = W[j][p] (one-time, tiny). ----
__global__ void wtrans_kernel(const float* __restrict__ Wq, const float* __restrict__ Wk,
                              const float* __restrict__ Wv, float* __restrict__ WqT,
                              float* __restrict__ WkT, float* __restrict__ WvT) {
    int idx = blockIdx.x * 256 + threadIdx.x;
    if (idx < AANG * AANG) {
        int p = idx / AANG;
        int j = idx - p * AANG;
        int src = j * AANG + p;
        WqT[idx] = Wq[src];
        WkT[idx] = Wk[src];
        WvT[idx] = Wv[src];
    }
}

// ---------------- QKV v2: block = (n, 4-row chunk); lanes j read WT coalesced.
// K written transposed: Kt[n][j][i]. ----
__global__ void qkv_kernel(const float* __restrict__ sino,
                           const float* __restrict__ WqT, const float* __restrict__ bq,
                           const float* __restrict__ WkT, const float* __restrict__ bk,
                           const float* __restrict__ WvT, const float* __restrict__ bv,
                           float* __restrict__ Q, float* __restrict__ Kt,
                           float* __restrict__ V) {
    __shared__ float srow[4][AANG];
    int blk = blockIdx.x;  // n*64 + i4
    int n = blk >> 6;
    int i0 = (blk & 63) * 4;
    int tid = threadIdx.x;  // 192
    if (tid < AANG) {
        for (int r = 0; r < 4; ++r)
            srow[r][tid] = sino[((size_t)(n * NN + i0 + r)) * AANG + tid];
    }
    __syncthreads();
    if (tid < AANG) {
        int j = tid;
        float bqv = bq[j], bkv = bk[j], bvv = bv[j];
        float aq0 = bqv, aq1 = bqv, aq2 = bqv, aq3 = bqv;
        float ak0 = bkv, ak1 = bkv, ak2 = bkv, ak3 = bkv;
        float av0 = bvv, av1 = bvv, av2 = bvv, av3 = bvv;
        for (int p = 0; p < AANG; ++p) {
            float wq = WqT[p * AANG + j];
            float wk = WkT[p * AANG + j];
            float wv = WvT[p * AANG + j];
            float s0 = srow[0][p], s1 = srow[1][p], s2 = srow[2][p], s3 = srow[3][p];
            aq0 += s0 * wq; aq1 += s1 * wq; aq2 += s2 * wq; aq3 += s3 * wq;
            ak0 += s0 * wk; ak1 += s1 * wk; ak2 += s2 * wk; ak3 += s3 * wk;
            av0 += s0 * wv; av1 += s1 * wv; av2 += s2 * wv; av3 += s3 * wv;
        }
        size_t qb = ((size_t)(n * NN + i0)) * AANG + j;
        Q[qb] = aq0; Q[qb + AANG] = aq1; Q[qb + 2 * AANG] = aq2; Q[qb + 3 * AANG] = aq3;
        V[qb] = av0; V[qb + AANG] = av1; V[qb + 2 * AANG] = av2; V[qb + 3 * AANG] = av3;
        size_t kb = ((size_t)(n * AANG + j)) * NN + i0;
        Kt[kb] = ak0; Kt[kb + 1] = ak1; Kt[kb + 2] = ak2; Kt[kb + 3] = ak3;
    }
}

// ---------------- Attention v2: block = (n, 2 query rows). Kt reads coalesced;
// att written transposed: att_t[n][j][i]. ----
__global__ void attn_kernel(const float* __restrict__ Q, const float* __restrict__ Kt,
                            const float* __restrict__ V, float* __restrict__ att_t) {
    __shared__ float qrow0[AANG], qrow1[AANG];
    __shared__ float red0[NN], red1[NN];
    __shared__ float prob0[NN], prob1[NN];
    int blk = blockIdx.x;  // n*128 + i2
    int n = blk >> 7;
    int i0 = (blk & 127) * 2;
    int tid = threadIdx.x;  // 256: key index k
    if (tid < AANG) {
        qrow0[tid] = Q[((size_t)(n * NN + i0)) * AANG + tid];
        qrow1[tid] = Q[((size_t)(n * NN + i0 + 1)) * AANG + tid];
    }
    __syncthreads();
    float dot0 = 0.0f, dot1 = 0.0f;
    for (int j = 0; j < AANG; ++j) {
        float kv = Kt[((size_t)(n * AANG + j)) * NN + tid];
        dot0 += qrow0[j] * kv;
        dot1 += qrow1[j] * kv;
    }
    float rs = sqrtf((float)AANG);
    float l0 = dot0 / rs, l1 = dot1 / rs;
    red0[tid] = l0; red1[tid] = l1;
    __syncthreads();
    for (int st = NN / 2; st > 0; st >>= 1) {
        if (tid < st) {
            red0[tid] = fmaxf(red0[tid], red0[tid + st]);
            red1[tid] = fmaxf(red1[tid], red1[tid + st]);
        }
        __syncthreads();
    }
    float mx0 = red0[0], mx1 = red1[0];
    __syncthreads();
    float e0 = expf(l0 - mx0), e1 = expf(l1 - mx1);
    red0[tid] = e0; red1[tid] = e1;
    __syncthreads();
    for (int st = NN / 2; st > 0; st >>= 1) {
        if (tid < st) {
            red0[tid] += red0[tid + st];
            red1[tid] += red1[tid + st];
        }
        __syncthreads();
    }
    float d0 = red0[0], d1 = red1[0];
    prob0[tid] = e0 / d0;
    prob1[tid] = e1 / d1;
    __syncthreads();
    if (tid < AANG) {
        float acc0 = 0.0f, acc1 = 0.0f;
        const float* vb = V + (size_t)n * NN * AANG + tid;
        for (int k = 0; k < NN; ++k) {
            float v = vb[(size_t)k * AANG];  // lanes j coalesced
            acc0 += prob0[k] * v;
            acc1 += prob1[k] * v;
        }
        size_t ob = ((size_t)(n * AANG + tid)) * NN + i0;
        att_t[ob] = acc0;
        att_t[ob + 1] = acc1;
    }
}

// ---------------- Ramp filter (128-tap symmetric conv), reads att_t coalesced,
// writes filt[n][a][i]. ----
__global__ void filter_kernel(const float* __restrict__ att_t, float* __restrict__ filt) {
    __shared__ float col[NN];
    __shared__ float coef[128];
    int blk = blockIdx.x;  // n*AANG + a
    int tid = threadIdx.x;
    col[tid] = att_t[(size_t)blk * NN + tid];
    if (tid < 128) {
        double d = (double)(2 * tid + 1);
        coef[tid] = (float)(-2.0 / (M_PI * M_PI * d * d));
    }
    __syncthreads();
    float acc = 0.5f * col[tid];
    for (int m = 0; m < 128; ++m) {
        int d = 2 * m + 1;
        float lo = (tid - d >= 0) ? col[tid - d] : 0.0f;
        float hi = (tid + d < NN) ? col[tid + d] : 0.0f;
        acc += coef[m] * (lo + hi);
    }
    filt[(size_t)blk * NN + tid] = acc;
}

// ---------------- Backprojection: 12-angle LDS chunks. ----
#define ACH 12
__global__ void backproj_kernel(const float* __restrict__ filt, float* __restrict__ out) {
    __shared__ float cols[ACH][NN];
    __shared__ float cs[AANG], sn[AANG];
    int blk = blockIdx.x;  // n*NN + r
    int n = blk >> 8;
    int r = blk & 255;
    int tid = threadIdx.x;  // column c
    if (tid < AANG) {
        float th = (float)((double)tid * (M_PI / 180.0));
        cs[tid] = cosf(th);
        sn[tid] = sinf(th);
    }
    float xr = (float)(r - 128);    // xpr (row - radius)
    float yr = (float)(tid - 128);  // ypr (col - radius)
    float acc = 0.0f;
    const float* fb = filt + (size_t)n * AANG * NN;
    for (int ch = 0; ch < AANG / ACH; ++ch) {
        __syncthreads();
        for (int q = 0; q < ACH; ++q)
            cols[q][tid] = fb[(size_t)(ch * ACH + q) * NN + tid];
        __syncthreads();
        for (int q = 0; q < ACH; ++q) {
            int aa = ch * ACH + q;
            float t = yr * cs[aa] - xr * sn[aa] + 128.0f;
            float i0f = floorf(t);
            int i0 = (int)i0f;
            float frac = t - i0f;
            int c0 = iclamp(i0, 0, NN - 1);
            int c1 = iclamp(i0 + 1, 0, NN - 1);
            float val = (1.0f - frac) * cols[q][c0] + frac * cols[q][c1];
            if (t >= 0.0f && t <= 255.0f) acc += val;
        }
    }
    bool inside = (xr * xr + yr * yr) <= 16384.0f;
    out[(size_t)blk * NN + tid] = inside ? acc * (float)(M_PI / 360.0) : 0.0f;
}

extern "C" void kernel_launch(void* const* d_in, const int* in_sizes, int n_in,
                              void* d_out, int out_size, void* d_ws, size_t ws_size,
                              hipStream_t stream) {
    const float* x  = (const float*)d_in[0];
    const float* Wq = (const float*)d_in[1];
    const float* bq = (const float*)d_in[2];
    const float* Wk = (const float*)d_in[3];
    const float* bk = (const float*)d_in[4];
    const float* Wv = (const float*)d_in[5];
    const float* bv = (const float*)d_in[6];
    float* out = (float*)d_out;
    float* ws = (float*)d_ws;

    const size_t SZ = (size_t)BCH * NN * AANG;  // 552960
    float* sino  = ws;
    float* Q     = sino + SZ;
    float* Kt    = Q + SZ;
    float* V     = Kt + SZ;
    float* att_t = V + SZ;
    float* WqT   = att_t + SZ;
    float* WkT   = WqT + AANG * AANG;
    float* WvT   = WkT + AANG * AANG;
    float* filt  = Q;  // alias: Q dead after attn, filter runs later on same stream

    wtrans_kernel<<<(AANG * AANG + 255) / 256, 256, 0, stream>>>(Wq, Wk, Wv, WqT, WkT, WvT);
    radon_kernel<<<BCH * AANG, NN, 0, stream>>>(x, sino);
    qkv_kernel<<<BCH * (NN / 4), 192, 0, stream>>>(sino, WqT, bq, WkT, bk, WvT, bv, Q, Kt, V);
    attn_kernel<<<BCH * (NN / 2), NN, 0, stream>>>(Q, Kt, V, att_t);
    filter_kernel<<<BCH * AANG, NN, 0, stream>>>(att_t, filt);
    backproj_kernel<<<BCH * NN, NN, 0, stream>>>(filt, out);
}

// Round 3
// 786.330 us; speedup vs baseline: 1.3023x; 1.0942x over previous
//
#include <hip/hip_runtime.h>

#define AANG 180
#define NN 256
#define BCH 12

#ifndef M_PI
#define M_PI 3.14159265358979323846
#endif

__device__ __forceinline__ int iclamp(int v, int lo, int hi) {
    return v < lo ? lo : (v > hi ? hi : v);
}

// ---------------- Radon v4: small-band LDS staging, division-free, analytic ranges.
// Bands over iy: blo = b*26 - 1, each covers iy in [blo, blo+25], stages rows
// [blo, blo+26] (27 rows x 259 cols = 28 KB -> 5 blocks/CU).
#define BAND 26
#define LROWS 27
#define LSTR 259
#define NBANDS 10

__device__ __forceinline__ int iy_of(int u, bool rev, float c, float dcon) {
    float fy = rev ? (float)(255 - u) : (float)u;
    return (int)floorf(__builtin_fmaf(c, fy, dcon));
}

__global__ void radon_kernel(const float* __restrict__ x, float* __restrict__ sino) {
    __shared__ float tile[LROWS * LSTR];
    int blk = blockIdx.x;
    int n = blk / AANG;
    int a = blk - n * AANG;
    const float* img = x + (size_t)n * NN * NN;
    int tid = threadIdx.x;  // output column fx
    float th = (float)((double)a * (M_PI / 180.0));
    float c = cosf(th), s = sinf(th);
    float fx = (float)tid;
    float kx = -128.0f * (c + s - 1.0f);
    float ky = -128.0f * (c - s - 1.0f);
    float dcon = -s * fx + ky;  // sy = fma(c, fy, dcon)
    float xcon = c * fx + kx;   // sx = fma(s, fy, xcon)
    bool rev = (c < 0.0f);      // fy(u) = rev ? 255-u : u  => sy nondecreasing in u
    float A = rev ? -c : c;     // slope of sy(u), > 0 always (min ~4e-8 at 90 deg)
    float B = rev ? __builtin_fmaf(c, 255.0f, dcon) : dcon;
    float acc = 0.0f;

    // u0: first u with iy(u) >= -1
    int u0;
    {
        float t = (-1.0f - B) / A;
        t = fminf(fmaxf(t, 0.0f), 256.0f);
        u0 = (int)t;
        while (u0 < 256 && iy_of(u0, rev, c, dcon) < -1) ++u0;
        while (u0 > 0 && iy_of(u0 - 1, rev, c, dcon) >= -1) --u0;
    }

    for (int b = 0; b < NBANDS; ++b) {
        int blo = b * BAND - 1;
        int bhi = blo + BAND - 1;
        if (b) __syncthreads();
        // stage rows [blo, blo+26], LDS col lc = global col + 1 (cols -1..257)
        for (int r = 0; r < LROWS; ++r) {
            int gr = blo + r;
            bool rok = (gr >= 0) && (gr < NN);
            const float* row = img + gr * NN;
            int gc = tid - 1;
            float v = (rok && gc >= 0) ? row[gc] : 0.0f;
            tile[r * LSTR + tid] = v;
            if (tid < 3) {
                int gc2 = 255 + tid;
                float v2 = (rok && gc2 < NN) ? row[gc2] : 0.0f;
                tile[r * LSTR + 256 + tid] = v2;
            }
        }
        __syncthreads();
        // ue: first u with iy(u) > bhi  (analytic guess + exact fixup)
        int ue;
        {
            float t = ((float)(bhi + 1) - B) / A;
            t = fminf(fmaxf(t, (float)u0), 256.0f);
            ue = (int)t;
            while (ue < 256 && iy_of(ue, rev, c, dcon) <= bhi) ++ue;
            while (ue > u0 && iy_of(ue - 1, rev, c, dcon) > bhi) --ue;
        }
        for (int u = u0; u < ue; ++u) {
            float fy = rev ? (float)(255 - u) : (float)u;
            float sy = __builtin_fmaf(c, fy, dcon);
            float sx = __builtin_fmaf(s, fy, xcon);
            float iyf = floorf(sy), ixf = floorf(sx);
            int iy = (int)iyf, ix = (int)ixf;
            float wy = sy - iyf, wx = sx - ixf;
            int lr = iclamp(iy - blo, 0, LROWS - 2);
            bool okx = (ix >= -1) && (ix <= NN);
            int lc = okx ? (ix + 1) : 0;
            const float* t0 = &tile[lr * LSTR + lc];
            float v00 = t0[0], v01 = t0[1];
            float v10 = t0[LSTR], v11 = t0[LSTR + 1];
            float wx1 = 1.0f - wx, wy1 = 1.0f - wy;
            float val = wy1 * (wx1 * v00 + wx * v01) + wy * (wx1 * v10 + wx * v11);
            acc += okx ? val : 0.0f;
        }
        u0 = ue;
    }
    sino[((size_t)(n * NN) + tid) * AANG + a] = acc;  // sino[n][x][a]
}

// ---------------- W transpose: WT[p][j] = W[j][p] (one-time, tiny). ----
__global__ void wtrans_kernel(const float* __restrict__ Wq, const float* __restrict__ Wk,
                              const float* __restrict__ Wv, float* __restrict__ WqT,
                              float* __restrict__ WkT, float* __restrict__ WvT) {
    int idx = blockIdx.x * 256 + threadIdx.x;
    if (idx < AANG * AANG) {
        int p = idx / AANG;
        int j = idx - p * AANG;
        int src = j * AANG + p;
        WqT[idx] = Wq[src];
        WkT[idx] = Wk[src];
        WvT[idx] = Wv[src];
    }
}

// ---------------- QKV: block = (n, 4-row chunk); lanes j read WT coalesced.
// K written transposed: Kt[n][j][i]. ----
__global__ void qkv_kernel(const float* __restrict__ sino,
                           const float* __restrict__ WqT, const float* __restrict__ bq,
                           const float* __restrict__ WkT, const float* __restrict__ bk,
                           const float* __restrict__ WvT, const float* __restrict__ bv,
                           float* __restrict__ Q, float* __restrict__ Kt,
                           float* __restrict__ V) {
    __shared__ float srow[4][AANG];
    int blk = blockIdx.x;  // n*64 + i4
    int n = blk >> 6;
    int i0 = (blk & 63) * 4;
    int tid = threadIdx.x;  // 192
    if (tid < AANG) {
        for (int r = 0; r < 4; ++r)
            srow[r][tid] = sino[((size_t)(n * NN + i0 + r)) * AANG + tid];
    }
    __syncthreads();
    if (tid < AANG) {
        int j = tid;
        float bqv = bq[j], bkv = bk[j], bvv = bv[j];
        float aq0 = bqv, aq1 = bqv, aq2 = bqv, aq3 = bqv;
        float ak0 = bkv, ak1 = bkv, ak2 = bkv, ak3 = bkv;
        float av0 = bvv, av1 = bvv, av2 = bvv, av3 = bvv;
        for (int p = 0; p < AANG; ++p) {
            float wq = WqT[p * AANG + j];
            float wk = WkT[p * AANG + j];
            float wv = WvT[p * AANG + j];
            float s0 = srow[0][p], s1 = srow[1][p], s2 = srow[2][p], s3 = srow[3][p];
            aq0 += s0 * wq; aq1 += s1 * wq; aq2 += s2 * wq; aq3 += s3 * wq;
            ak0 += s0 * wk; ak1 += s1 * wk; ak2 += s2 * wk; ak3 += s3 * wk;
            av0 += s0 * wv; av1 += s1 * wv; av2 += s2 * wv; av3 += s3 * wv;
        }
        size_t qb = ((size_t)(n * NN + i0)) * AANG + j;
        Q[qb] = aq0; Q[qb + AANG] = aq1; Q[qb + 2 * AANG] = aq2; Q[qb + 3 * AANG] = aq3;
        V[qb] = av0; V[qb + AANG] = av1; V[qb + 2 * AANG] = av2; V[qb + 3 * AANG] = av3;
        size_t kb = ((size_t)(n * AANG + j)) * NN + i0;
        Kt[kb] = ak0; Kt[kb + 1] = ak1; Kt[kb + 2] = ak2; Kt[kb + 3] = ak3;
    }
}

// ---------------- Attention: block = (n, 2 query rows). Kt reads coalesced;
// att written transposed: att_t[n][j][i]. ----
__global__ void attn_kernel(const float* __restrict__ Q, const float* __restrict__ Kt,
                            const float* __restrict__ V, float* __restrict__ att_t) {
    __shared__ float qrow0[AANG], qrow1[AANG];
    __shared__ float red0[NN], red1[NN];
    __shared__ float prob0[NN], prob1[NN];
    int blk = blockIdx.x;  // n*128 + i2
    int n = blk >> 7;
    int i0 = (blk & 127) * 2;
    int tid = threadIdx.x;  // 256: key index k
    if (tid < AANG) {
        qrow0[tid] = Q[((size_t)(n * NN + i0)) * AANG + tid];
        qrow1[tid] = Q[((size_t)(n * NN + i0 + 1)) * AANG + tid];
    }
    __syncthreads();
    float dot0 = 0.0f, dot1 = 0.0f;
    for (int j = 0; j < AANG; ++j) {
        float kv = Kt[((size_t)(n * AANG + j)) * NN + tid];
        dot0 += qrow0[j] * kv;
        dot1 += qrow1[j] * kv;
    }
    float rs = sqrtf((float)AANG);
    float l0 = dot0 / rs, l1 = dot1 / rs;
    red0[tid] = l0; red1[tid] = l1;
    __syncthreads();
    for (int st = NN / 2; st > 0; st >>= 1) {
        if (tid < st) {
            red0[tid] = fmaxf(red0[tid], red0[tid + st]);
            red1[tid] = fmaxf(red1[tid], red1[tid + st]);
        }
        __syncthreads();
    }
    float mx0 = red0[0], mx1 = red1[0];
    __syncthreads();
    float e0 = expf(l0 - mx0), e1 = expf(l1 - mx1);
    red0[tid] = e0; red1[tid] = e1;
    __syncthreads();
    for (int st = NN / 2; st > 0; st >>= 1) {
        if (tid < st) {
            red0[tid] += red0[tid + st];
            red1[tid] += red1[tid + st];
        }
        __syncthreads();
    }
    float d0 = red0[0], d1 = red1[0];
    prob0[tid] = e0 / d0;
    prob1[tid] = e1 / d1;
    __syncthreads();
    if (tid < AANG) {
        float acc0 = 0.0f, acc1 = 0.0f;
        const float* vb = V + (size_t)n * NN * AANG + tid;
        for (int k = 0; k < NN; ++k) {
            float v = vb[(size_t)k * AANG];  // lanes j coalesced
            acc0 += prob0[k] * v;
            acc1 += prob1[k] * v;
        }
        size_t ob = ((size_t)(n * AANG + tid)) * NN + i0;
        att_t[ob] = acc0;
        att_t[ob + 1] = acc1;
    }
}

// ---------------- Ramp filter (128-tap symmetric conv), reads att_t coalesced,
// writes filt[n][a][i]. ----
__global__ void filter_kernel(const float* __restrict__ att_t, float* __restrict__ filt) {
    __shared__ float col[NN];
    __shared__ float coef[128];
    int blk = blockIdx.x;  // n*AANG + a
    int tid = threadIdx.x;
    col[tid] = att_t[(size_t)blk * NN + tid];
    if (tid < 128) {
        double d = (double)(2 * tid + 1);
        coef[tid] = (float)(-2.0 / (M_PI * M_PI * d * d));
    }
    __syncthreads();
    float acc = 0.5f * col[tid];
    for (int m = 0; m < 128; ++m) {
        int d = 2 * m + 1;
        float lo = (tid - d >= 0) ? col[tid - d] : 0.0f;
        float hi = (tid + d < NN) ? col[tid + d] : 0.0f;
        acc += coef[m] * (lo + hi);
    }
    filt[(size_t)blk * NN + tid] = acc;
}

// ---------------- Backprojection: 12-angle LDS chunks. ----
#define ACH 12
__global__ void backproj_kernel(const float* __restrict__ filt, float* __restrict__ out) {
    __shared__ float cols[ACH][NN];
    __shared__ float cs[AANG], sn[AANG];
    int blk = blockIdx.x;  // n*NN + r
    int n = blk >> 8;
    int r = blk & 255;
    int tid = threadIdx.x;  // column c
    if (tid < AANG) {
        float th = (float)((double)tid * (M_PI / 180.0));
        cs[tid] = cosf(th);
        sn[tid] = sinf(th);
    }
    float xr = (float)(r - 128);    // xpr (row - radius)
    float yr = (float)(tid - 128);  // ypr (col - radius)
    float acc = 0.0f;
    const float* fb = filt + (size_t)n * AANG * NN;
    for (int ch = 0; ch < AANG / ACH; ++ch) {
        __syncthreads();
        for (int q = 0; q < ACH; ++q)
            cols[q][tid] = fb[(size_t)(ch * ACH + q) * NN + tid];
        __syncthreads();
        for (int q = 0; q < ACH; ++q) {
            int aa = ch * ACH + q;
            float t = yr * cs[aa] - xr * sn[aa] + 128.0f;
            float i0f = floorf(t);
            int i0 = (int)i0f;
            float frac = t - i0f;
            int c0 = iclamp(i0, 0, NN - 1);
            int c1 = iclamp(i0 + 1, 0, NN - 1);
            float val = (1.0f - frac) * cols[q][c0] + frac * cols[q][c1];
            if (t >= 0.0f && t <= 255.0f) acc += val;
        }
    }
    bool inside = (xr * xr + yr * yr) <= 16384.0f;
    out[(size_t)blk * NN + tid] = inside ? acc * (float)(M_PI / 360.0) : 0.0f;
}

extern "C" void kernel_launch(void* const* d_in, const int* in_sizes, int n_in,
                              void* d_out, int out_size, void* d_ws, size_t ws_size,
                              hipStream_t stream) {
    const float* x  = (const float*)d_in[0];
    const float* Wq = (const float*)d_in[1];
    const float* bq = (const float*)d_in[2];
    const float* Wk = (const float*)d_in[3];
    const float* bk = (const float*)d_in[4];
    const float* Wv = (const float*)d_in[5];
    const float* bv = (const float*)d_in[6];
    float* out = (float*)d_out;
    float* ws = (float*)d_ws;

    const size_t SZ = (size_t)BCH * NN * AANG;  // 552960
    float* sino  = ws;
    float* Q     = sino + SZ;
    float* Kt    = Q + SZ;
    float* V     = Kt + SZ;
    float* att_t = V + SZ;
    float* WqT   = att_t + SZ;
    float* WkT   = WqT + AANG * AANG;
    float* WvT   = WkT + AANG * AANG;
    float* filt  = Q;  // alias: Q dead after attn

    wtrans_kernel<<<(AANG * AANG + 255) / 256, 256, 0, stream>>>(Wq, Wk, Wv, WqT, WkT, WvT);
    radon_kernel<<<BCH * AANG, NN, 0, stream>>>(x, sino);
    qkv_kernel<<<BCH * (NN / 4), 192, 0, stream>>>(sino, WqT, bq, WkT, bk, WvT, bv, Q, Kt, V);
    attn_kernel<<<BCH * (NN / 2), NN, 0, stream>>>(Q, Kt, V, att_t);
    filter_kernel<<<BCH * AANG, NN, 0, stream>>>(att_t, filt);
    backproj_kernel<<<BCH * NN, NN, 0, stream>>>(filt, out);
}

// Round 4
// 477.247 us; speedup vs baseline: 2.1456x; 1.6476x over previous
//
#include <hip/hip_runtime.h>

#define AANG 180
#define NN 256
#define BCH 12

#ifndef M_PI
#define M_PI 3.14159265358979323846
#endif

__device__ __forceinline__ int iclamp(int v, int lo, int hi) {
    return v < lo ? lo : (v > hi ? hi : v);
}

// ---------------- Radon v5: half-image LDS residency, uniform predicated loops.
// Block = (n, half, angle-group of ~6 strided angles); 1024 threads = 256 x-cols
// x 4 u-quarters. Stage 129/130 rows once (134.7 KB LDS), then per angle a
// uniform 64-iter loop, per-sample predication. Partial sums written per half:
// partial[h][n][a][x] (coalesced); qkv sums the two halves.
#define LSTR 259
#define LROWSMAX 130

__global__ __launch_bounds__(1024, 1)
void radon_kernel(const float* __restrict__ x, float* __restrict__ partial) {
    __shared__ float tile[LROWSMAX * LSTR];  // 134,680 B
    __shared__ float red[1024];              // + 4 KB
    int blk = blockIdx.x;        // 12n x 2h x 32g
    int g = blk & 31;
    int h = (blk >> 5) & 1;
    int n = blk >> 6;
    int tid = threadIdx.x;
    int lx = tid & 255;   // output column
    int qid = tid >> 8;   // u-quarter
    int R0 = h ? 127 : -1;          // first staged row
    int nrows = h ? 130 : 129;      // stage rows [R0, R0+nrows-1]
    float Ylo = h ? 127.0f : -1.0f; // predicate iy in [Ylo, Yhi]
    float Yhi = h ? 255.0f : 126.0f;
    const float* img = x + (size_t)n * NN * NN;

    // Stage: LDS col lc = global col + 1 (cols -1..257, OOB = 0).
    for (int rr = qid; rr < nrows; rr += 4) {
        int gr = R0 + rr;
        bool rok = (gr >= 0) && (gr < NN);
        const float* row = img + gr * NN;
        int gc = lx - 1;
        tile[rr * LSTR + lx] = (rok && gc >= 0) ? row[gc] : 0.0f;
        if (lx < 3) {
            int gc2 = 255 + lx;
            tile[rr * LSTR + 256 + lx] = (rok && gc2 < NN) ? row[gc2] : 0.0f;
        }
    }
    __syncthreads();

    float fx = (float)lx;
    int u0 = qid * 64;
    for (int aa = 0; aa < 6; ++aa) {
        int a = g + aa * 32;  // strided angle assignment
        if (a >= AANG) break; // uniform across block
        float th = (float)((double)a * (M_PI / 180.0));
        float c = cosf(th), s = sinf(th);
        float kx = -128.0f * (c + s - 1.0f);
        float ky = -128.0f * (c - s - 1.0f);
        float xcon = c * fx + kx;   // sx = fma(s, fy, xcon)
        float dcon = -s * fx + ky;  // sy = fma(c, fy, dcon)
        float acc = 0.0f;
#pragma unroll 4
        for (int i = 0; i < 64; ++i) {
            float fy = (float)(u0 + i);
            float sy = __builtin_fmaf(c, fy, dcon);
            float sx = __builtin_fmaf(s, fy, xcon);
            float iyf = floorf(sy), ixf = floorf(sx);
            if (iyf >= Ylo && iyf <= Yhi && ixf >= -1.0f && ixf <= 255.0f) {
                float wy = sy - iyf, wx = sx - ixf;
                int lr = (int)iyf - R0;  // in [0, nrows-2]
                int lc = (int)ixf + 1;   // in [0, 256]
                const float* t0 = &tile[lr * LSTR + lc];
                float v00 = t0[0], v01 = t0[1];
                float v10 = t0[LSTR], v11 = t0[LSTR + 1];
                float wx1 = 1.0f - wx, wy1 = 1.0f - wy;
                acc += wy1 * (wx1 * v00 + wx * v01) + wy * (wx1 * v10 + wx * v11);
            }
        }
        red[tid] = acc;
        __syncthreads();
        if (tid < 256) {
            float ssum = red[tid] + red[tid + 256] + red[tid + 512] + red[tid + 768];
            partial[(((size_t)h * BCH + n) * AANG + a) * NN + tid] = ssum;
        }
        __syncthreads();
    }
}

// ---------------- W transpose: WT[p][j] = W[j][p] (one-time, tiny). ----
__global__ void wtrans_kernel(const float* __restrict__ Wq, const float* __restrict__ Wk,
                              const float* __restrict__ Wv, float* __restrict__ WqT,
                              float* __restrict__ WkT, float* __restrict__ WvT) {
    int idx = blockIdx.x * 256 + threadIdx.x;
    if (idx < AANG * AANG) {
        int p = idx / AANG;
        int j = idx - p * AANG;
        int src = j * AANG + p;
        WqT[idx] = Wq[src];
        WkT[idx] = Wk[src];
        WvT[idx] = Wv[src];
    }
}

// ---------------- QKV: block = (n, 4-row chunk). Stages sino rows by summing the
// two radon half-partials (small scattered L2 gathers). K written transposed. ----
__global__ void qkv_kernel(const float* __restrict__ partial,
                           const float* __restrict__ WqT, const float* __restrict__ bq,
                           const float* __restrict__ WkT, const float* __restrict__ bk,
                           const float* __restrict__ WvT, const float* __restrict__ bv,
                           float* __restrict__ Q, float* __restrict__ Kt,
                           float* __restrict__ V) {
    __shared__ float srow[4][AANG];
    int blk = blockIdx.x;  // n*64 + i4
    int n = blk >> 6;
    int i0 = (blk & 63) * 4;
    int tid = threadIdx.x;  // 192
    const size_t HOFF = (size_t)BCH * AANG * NN;
    if (tid < AANG) {
        for (int r = 0; r < 4; ++r) {
            size_t idx = (((size_t)n) * AANG + tid) * NN + (i0 + r);
            srow[r][tid] = partial[idx] + partial[idx + HOFF];
        }
    }
    __syncthreads();
    if (tid < AANG) {
        int j = tid;
        float bqv = bq[j], bkv = bk[j], bvv = bv[j];
        float aq0 = bqv, aq1 = bqv, aq2 = bqv, aq3 = bqv;
        float ak0 = bkv, ak1 = bkv, ak2 = bkv, ak3 = bkv;
        float av0 = bvv, av1 = bvv, av2 = bvv, av3 = bvv;
        for (int p = 0; p < AANG; ++p) {
            float wq = WqT[p * AANG + j];
            float wk = WkT[p * AANG + j];
            float wv = WvT[p * AANG + j];
            float s0 = srow[0][p], s1 = srow[1][p], s2 = srow[2][p], s3 = srow[3][p];
            aq0 += s0 * wq; aq1 += s1 * wq; aq2 += s2 * wq; aq3 += s3 * wq;
            ak0 += s0 * wk; ak1 += s1 * wk; ak2 += s2 * wk; ak3 += s3 * wk;
            av0 += s0 * wv; av1 += s1 * wv; av2 += s2 * wv; av3 += s3 * wv;
        }
        size_t qb = ((size_t)(n * NN + i0)) * AANG + j;
        Q[qb] = aq0; Q[qb + AANG] = aq1; Q[qb + 2 * AANG] = aq2; Q[qb + 3 * AANG] = aq3;
        V[qb] = av0; V[qb + AANG] = av1; V[qb + 2 * AANG] = av2; V[qb + 3 * AANG] = av3;
        size_t kb = ((size_t)(n * AANG + j)) * NN + i0;
        Kt[kb] = ak0; Kt[kb + 1] = ak1; Kt[kb + 2] = ak2; Kt[kb + 3] = ak3;
    }
}

// ---------------- Attention: block = (n, 2 query rows). att written transposed. ----
__global__ void attn_kernel(const float* __restrict__ Q, const float* __restrict__ Kt,
                            const float* __restrict__ V, float* __restrict__ att_t) {
    __shared__ float qrow0[AANG], qrow1[AANG];
    __shared__ float red0[NN], red1[NN];
    __shared__ float prob0[NN], prob1[NN];
    int blk = blockIdx.x;  // n*128 + i2
    int n = blk >> 7;
    int i0 = (blk & 127) * 2;
    int tid = threadIdx.x;  // 256: key index k
    if (tid < AANG) {
        qrow0[tid] = Q[((size_t)(n * NN + i0)) * AANG + tid];
        qrow1[tid] = Q[((size_t)(n * NN + i0 + 1)) * AANG + tid];
    }
    __syncthreads();
    float dot0 = 0.0f, dot1 = 0.0f;
    for (int j = 0; j < AANG; ++j) {
        float kv = Kt[((size_t)(n * AANG + j)) * NN + tid];
        dot0 += qrow0[j] * kv;
        dot1 += qrow1[j] * kv;
    }
    float rs = sqrtf((float)AANG);
    float l0 = dot0 / rs, l1 = dot1 / rs;
    red0[tid] = l0; red1[tid] = l1;
    __syncthreads();
    for (int st = NN / 2; st > 0; st >>= 1) {
        if (tid < st) {
            red0[tid] = fmaxf(red0[tid], red0[tid + st]);
            red1[tid] = fmaxf(red1[tid], red1[tid + st]);
        }
        __syncthreads();
    }
    float mx0 = red0[0], mx1 = red1[0];
    __syncthreads();
    float e0 = expf(l0 - mx0), e1 = expf(l1 - mx1);
    red0[tid] = e0; red1[tid] = e1;
    __syncthreads();
    for (int st = NN / 2; st > 0; st >>= 1) {
        if (tid < st) {
            red0[tid] += red0[tid + st];
            red1[tid] += red1[tid + st];
        }
        __syncthreads();
    }
    float d0 = red0[0], d1 = red1[0];
    prob0[tid] = e0 / d0;
    prob1[tid] = e1 / d1;
    __syncthreads();
    if (tid < AANG) {
        float acc0 = 0.0f, acc1 = 0.0f;
        const float* vb = V + (size_t)n * NN * AANG + tid;
        for (int k = 0; k < NN; ++k) {
            float v = vb[(size_t)k * AANG];
            acc0 += prob0[k] * v;
            acc1 += prob1[k] * v;
        }
        size_t ob = ((size_t)(n * AANG + tid)) * NN + i0;
        att_t[ob] = acc0;
        att_t[ob + 1] = acc1;
    }
}

// ---------------- Ramp filter (128-tap symmetric conv). ----
__global__ void filter_kernel(const float* __restrict__ att_t, float* __restrict__ filt) {
    __shared__ float col[NN];
    __shared__ float coef[128];
    int blk = blockIdx.x;  // n*AANG + a
    int tid = threadIdx.x;
    col[tid] = att_t[(size_t)blk * NN + tid];
    if (tid < 128) {
        double d = (double)(2 * tid + 1);
        coef[tid] = (float)(-2.0 / (M_PI * M_PI * d * d));
    }
    __syncthreads();
    float acc = 0.5f * col[tid];
    for (int m = 0; m < 128; ++m) {
        int d = 2 * m + 1;
        float lo = (tid - d >= 0) ? col[tid - d] : 0.0f;
        float hi = (tid + d < NN) ? col[tid + d] : 0.0f;
        acc += coef[m] * (lo + hi);
    }
    filt[(size_t)blk * NN + tid] = acc;
}

// ---------------- Backprojection: 12-angle LDS chunks. ----
#define ACH 12
__global__ void backproj_kernel(const float* __restrict__ filt, float* __restrict__ out) {
    __shared__ float cols[ACH][NN];
    __shared__ float cs[AANG], sn[AANG];
    int blk = blockIdx.x;  // n*NN + r
    int n = blk >> 8;
    int r = blk & 255;
    int tid = threadIdx.x;  // column c
    if (tid < AANG) {
        float th = (float)((double)tid * (M_PI / 180.0));
        cs[tid] = cosf(th);
        sn[tid] = sinf(th);
    }
    float xr = (float)(r - 128);
    float yr = (float)(tid - 128);
    float acc = 0.0f;
    const float* fb = filt + (size_t)n * AANG * NN;
    for (int ch = 0; ch < AANG / ACH; ++ch) {
        __syncthreads();
        for (int q = 0; q < ACH; ++q)
            cols[q][tid] = fb[(size_t)(ch * ACH + q) * NN + tid];
        __syncthreads();
        for (int q = 0; q < ACH; ++q) {
            int aa = ch * ACH + q;
            float t = yr * cs[aa] - xr * sn[aa] + 128.0f;
            float i0f = floorf(t);
            int i0 = (int)i0f;
            float frac = t - i0f;
            int c0 = iclamp(i0, 0, NN - 1);
            int c1 = iclamp(i0 + 1, 0, NN - 1);
            float val = (1.0f - frac) * cols[q][c0] + frac * cols[q][c1];
            if (t >= 0.0f && t <= 255.0f) acc += val;
        }
    }
    bool inside = (xr * xr + yr * yr) <= 16384.0f;
    out[(size_t)blk * NN + tid] = inside ? acc * (float)(M_PI / 360.0) : 0.0f;
}

extern "C" void kernel_launch(void* const* d_in, const int* in_sizes, int n_in,
                              void* d_out, int out_size, void* d_ws, size_t ws_size,
                              hipStream_t stream) {
    const float* x  = (const float*)d_in[0];
    const float* Wq = (const float*)d_in[1];
    const float* bq = (const float*)d_in[2];
    const float* Wk = (const float*)d_in[3];
    const float* bk = (const float*)d_in[4];
    const float* Wv = (const float*)d_in[5];
    const float* bv = (const float*)d_in[6];
    float* out = (float*)d_out;
    float* ws = (float*)d_ws;

    const size_t SZ = (size_t)BCH * NN * AANG;  // 552960 floats
    float* P     = ws;           // partial[2][n][a][x]: 2*SZ
    float* Q     = P + 2 * SZ;
    float* Kt    = Q + SZ;
    float* V     = Kt + SZ;
    float* att_t = V + SZ;       // total 6*SZ = 13.3 MB
    float* WqT   = att_t;        // alias: W-transposes dead before attn writes att_t
    float* WkT   = WqT + AANG * AANG;
    float* WvT   = WkT + AANG * AANG;
    float* filt  = P;            // alias: partials dead after qkv

    wtrans_kernel<<<(AANG * AANG + 255) / 256, 256, 0, stream>>>(Wq, Wk, Wv, WqT, WkT, WvT);
    radon_kernel<<<BCH * 2 * 32, 1024, 0, stream>>>(x, P);
    qkv_kernel<<<BCH * (NN / 4), 192, 0, stream>>>(P, WqT, bq, WkT, bk, WvT, bv, Q, Kt, V);
    attn_kernel<<<BCH * (NN / 2), NN, 0, stream>>>(Q, Kt, V, att_t);
    filter_kernel<<<BCH * AANG, NN, 0, stream>>>(att_t, filt);
    backproj_kernel<<<BCH * NN, NN, 0, stream>>>(filt, out);
}